// Round 4
// baseline (1171.187 us; speedup 1.0000x reference)
//
#include <hip/hip_runtime.h>
#include <hip/hip_bf16.h>

// Problem constants
#define N_CELLS   3872
#define NCLS      80
#define NFLAT     309760        // 3872*80
#define FH        128
#define FW        192
#define HW        24576         // 128*192
#define WORDS     384           // HW/64
#define PRE       500
#define OH        512
#define OW        768
#define OPIX      393216        // 512*768
#define MAXI      100
#define NBUCKET   16384
#define COLCAP    4096

// Workspace byte offsets (all 8B aligned)
#define OFF_HIST      0          // u32[16384]
#define OFF_CNT       65536      // u32[16] [0]=collect cnt [1]=B [2]=hist ticket [4]=maskstats ticket [5]=compcoef ticket
#define OFF_KEYBUF    65600      // u64[4096]
#define OFF_EGIDX     98368      // i32[512]
#define OFF_ELABEL    100416     // i32[512]
#define OFF_ECOUNT    102464     // i32[512]
#define OFF_TKSCORE   104512     // f32[512]
#define OFF_ESCORE1   106560     // f64[512]
#define OFF_ORDER1    110656     // i32[512]
#define OFF_SCORES    112704     // f64[512]
#define OFF_NS        116800     // f64[512]
#define OFF_FINALE    120896     // i32[128]
#define OFF_BOXESI    121408     // i32[400]
#define OFF_DONE      123008     // u32[128]
#define OFF_PACKED    123520     // u64[500*384]
#define OFF_DMAT      1659520    // f32[500*500]
// total ~2.66 MB

// upsample decomposition: each block = exactly 16 output rows
#define UPS_BLOCKS    32
#define UPS_GPB       3072      // (OPIX/4)/UPS_BLOCKS
#define UPS_ITERS     12        // UPS_GPB/256

typedef float f4_t __attribute__((ext_vector_type(4)));

__device__ __forceinline__ float stride_of(int g) {
    return (g < 2896) ? 8.0f : (g < 3472) ? 16.0f : 32.0f;
}

__device__ __forceinline__ int bucket_of(float v) {
    int b = (int)((v - 0.1f) * (16384.0f / 0.9f));
    return min(max(b, 0), NBUCKET - 1);
}

// deposit 16 low bits of x to every 4th bit position of a u64
__device__ __forceinline__ unsigned long long spread4(unsigned x) {
    unsigned long long v = (unsigned long long)(x & 0xFFFFu);
    v = (v | (v << 24)) & 0x000000FF000000FFull;
    v = (v | (v << 12)) & 0x000F000F000F000Full;
    v = (v | (v << 6))  & 0x0303030303030303ull;
    v = (v | (v << 3))  & 0x1111111111111111ull;
    return v;
}

__device__ __forceinline__ bool before_key(unsigned long long as, int ai,
                                           unsigned long long bs, int bi) {
    return (as > bs) || (as == bs && ai < bi);
}

// ---------------- init ----------------
__global__ void k_init(unsigned* hist, unsigned* counters, int* boxes, unsigned* done) {
    int i = blockIdx.x * blockDim.x + threadIdx.x;
    if (i < NBUCKET) hist[i] = 0u;
    if (i < 16) counters[i] = 0u;
    if (i < 128) done[i] = 0u;
    if (i < MAXI) {
        boxes[4*i+0] = OW;   // xmin sentinel (matches ref empty-mask result)
        boxes[4*i+1] = OH;
        boxes[4*i+2] = 0;
        boxes[4*i+3] = 0;
    }
}

// ---------------- histogram + (last block) find bucket threshold B ----------------
__global__ __launch_bounds__(256) void k_hist(const float4* __restrict__ cate4,
                                              unsigned* __restrict__ hist,
                                              unsigned* __restrict__ counters) {
    int i = blockIdx.x * blockDim.x + threadIdx.x;
    if (i < NFLAT / 4) {
        float4 v = cate4[i];
        if (v.x > 0.1f) atomicAdd(&hist[bucket_of(v.x)], 1u);
        if (v.y > 0.1f) atomicAdd(&hist[bucket_of(v.y)], 1u);
        if (v.z > 0.1f) atomicAdd(&hist[bucket_of(v.z)], 1u);
        if (v.w > 0.1f) atomicAdd(&hist[bucket_of(v.w)], 1u);
    }
    __shared__ int amLast;
    __threadfence();
    __syncthreads();
    if (threadIdx.x == 0)
        amLast = (atomicAdd(&counters[2], 1u) == gridDim.x - 1);
    __syncthreads();
    if (!amLast) return;
    __threadfence();
    // findB with 256 threads
    __shared__ unsigned part[256];
    int t = threadIdx.x;
    unsigned s = 0;
    for (int k = 0; k < 64; k++) s += hist[t * 64 + k];
    part[t] = s;
    __syncthreads();
    if (t == 0) {
        unsigned cum = 0;
        for (int c = 255; c >= 0; c--) {
            if (cum + part[c] >= (unsigned)PRE) {
                unsigned cum2 = cum;
                int b = c * 64 + 63;
                for (; b >= c * 64; b--) {
                    cum2 += hist[b];
                    if (cum2 >= (unsigned)PRE) break;
                }
                counters[1] = (unsigned)((b < c * 64) ? c * 64 : b);
                return;
            }
            cum += part[c];
        }
        counters[1] = 0u;
    }
}

// ---------------- collect candidates in buckets >= B (float4) ----------------
__global__ void k_collect(const float4* __restrict__ cate4, unsigned* counters,
                          unsigned long long* __restrict__ keybuf) {
    int i = blockIdx.x * blockDim.x + threadIdx.x;
    if (i >= NFLAT / 4) return;
    float4 v = cate4[i];
    int B = (int)counters[1];
    int base = 4 * i;
    float vv[4] = {v.x, v.y, v.z, v.w};
    #pragma unroll
    for (int c = 0; c < 4; c++) {
        float f = vv[c];
        if (f > 0.1f && bucket_of(f) >= B) {
            unsigned pos = atomicAdd(&counters[0], 1u);
            if (pos < COLCAP) {
                unsigned fb = __float_as_uint(f);
                unsigned idx = (unsigned)(base + c);
                keybuf[pos] = ((unsigned long long)fb << 32) | (unsigned long long)(0xFFFFFFFFu - idx);
            }
        }
    }
}

// ---------------- sort collected (dynamic pow2 size) desc, emit top-500 ----------------
__global__ __launch_bounds__(1024) void k_sort_collect(const unsigned long long* __restrict__ keybuf,
                                                       const unsigned* counters,
                                                       int* e_gidx, int* e_label, float* tk_score) {
    __shared__ unsigned long long k[COLCAP];
    int t = threadIdx.x;
    unsigned cnt = counters[0];
    if (cnt > COLCAP) cnt = COLCAP;
    int m = 512;
    while (m < (int)cnt) m <<= 1;
    for (int i = t; i < m; i += 1024) k[i] = (i < (int)cnt) ? keybuf[i] : 0ull;
    __syncthreads();
    for (int sz = 2; sz <= m; sz <<= 1) {
        for (int j = sz >> 1; j > 0; j >>= 1) {
            for (int i = t; i < m; i += 1024) {
                int ixj = i ^ j;
                if (ixj > i) {
                    bool up = ((i & sz) == 0);
                    unsigned long long a = k[i], b = k[ixj];
                    bool sw = up ? (a < b) : (a > b);   // descending
                    if (sw) { k[i] = b; k[ixj] = a; }
                }
            }
            __syncthreads();
        }
    }
    if (t < PRE) {
        unsigned long long key = k[t];
        if (key == 0ull) {
            e_gidx[t] = 0; e_label[t] = 0; tk_score[t] = -1.0f;
        } else {
            unsigned idx = 0xFFFFFFFFu - (unsigned)(key & 0xFFFFFFFFull);
            e_gidx[t] = (int)(idx / NCLS);
            e_label[t] = (int)(idx % NCLS);
            tk_score[t] = __uint_as_float((unsigned)(key >> 32));
        }
    }
}

// ---------------- per-candidate mask stats + bit-pack + (last block) sort1 ----------------
__global__ __launch_bounds__(256) void k_maskstats(const float* __restrict__ seg,
                                                   const int* __restrict__ e_gidx,
                                                   const float* __restrict__ tk_score,
                                                   unsigned long long* __restrict__ packed,
                                                   int* __restrict__ e_count,
                                                   double* __restrict__ e_score1,
                                                   unsigned* __restrict__ counters,
                                                   int* __restrict__ order1,
                                                   double* __restrict__ score_s) {
    int e = blockIdx.x;
    const float4* row4 = (const float4*)(seg + (size_t)e_gidx[e] * HW);
    int t = threadIdx.x;
    int lane = t & 63;
    int wv = t >> 6;
    int w = lane >> 4;
    int sh = 16 * w;
    double lsum = 0.0;
    int lcnt = 0;
    #pragma unroll 4
    for (int k = 0; k < 24; k++) {
        int p4 = t + k * 256;
        float4 v = row4[p4];
        unsigned nib = (v.x > 0.5f ? 1u : 0u) | (v.y > 0.5f ? 2u : 0u) |
                       (v.z > 0.5f ? 4u : 0u) | (v.w > 0.5f ? 8u : 0u);
        unsigned long long b0 = __ballot(nib & 1u);
        unsigned long long b1 = __ballot(nib & 2u);
        unsigned long long b2 = __ballot(nib & 4u);
        unsigned long long b3 = __ballot(nib & 8u);
        unsigned long long word = spread4((unsigned)(b0 >> sh))
                                | (spread4((unsigned)(b1 >> sh)) << 1)
                                | (spread4((unsigned)(b2 >> sh)) << 2)
                                | (spread4((unsigned)(b3 >> sh)) << 3);
        if ((lane & 15) == 0) packed[(size_t)e * WORDS + (k * 16 + wv * 4 + w)] = word;
        if (v.x > 0.5f) lsum += (double)v.x;
        if (v.y > 0.5f) lsum += (double)v.y;
        if (v.z > 0.5f) lsum += (double)v.z;
        if (v.w > 0.5f) lsum += (double)v.w;
        lcnt += __popc(nib);
    }
    for (int off = 32; off > 0; off >>= 1) {
        lsum += __shfl_down(lsum, off);
        lcnt += __shfl_down(lcnt, off);
    }
    __shared__ double ssum[4];
    __shared__ int scnt[4];
    if (lane == 0) { ssum[wv] = lsum; scnt[wv] = lcnt; }
    __syncthreads();
    if (t == 0) {
        double sum = ssum[0] + ssum[1] + ssum[2] + ssum[3];
        int cnt = scnt[0] + scnt[1] + scnt[2] + scnt[3];
        double segsc = sum / (double)max(cnt, 1);
        float sc = tk_score[e];
        bool keep = (sc > 0.1f) && ((float)cnt > stride_of(e_gidx[e]));
        e_count[e] = cnt;
        e_score1[e] = keep ? ((double)sc * segsc) : 0.0;
    }
    // ---- ticket: last block runs sort1 ----
    __shared__ int amLast;
    __threadfence();
    __syncthreads();
    if (t == 0) amLast = (atomicAdd(&counters[4], 1u) == gridDim.x - 1);
    __syncthreads();
    if (!amLast) return;
    __threadfence();
    __shared__ unsigned long long sb[512];
    __shared__ int si[512];
    for (int i = t; i < 512; i += 256) {
        sb[i] = (i < PRE) ? (unsigned long long)__double_as_longlong(e_score1[i]) : 0ull;
        si[i] = i;
    }
    __syncthreads();
    for (int sz = 2; sz <= 512; sz <<= 1) {
        for (int j = sz >> 1; j > 0; j >>= 1) {
            for (int i = t; i < 512; i += 256) {
                int ixj = i ^ j;
                if (ixj > i) {
                    unsigned long long as = sb[i], bs = sb[ixj];
                    int ai = si[i], bi = si[ixj];
                    bool up = ((i & sz) == 0);
                    bool aB = before_key(as, ai, bs, bi);
                    bool sw = up ? (!aB) : aB;
                    if (sw) { sb[i] = bs; sb[ixj] = as; si[i] = bi; si[ixj] = ai; }
                }
            }
            __syncthreads();
        }
    }
    for (int i = t; i < PRE; i += 256) {
        order1[i] = si[i];
        score_s[i] = __longlong_as_double((long long)sb[i]);
    }
}

// ---------------- decay_iou matrix: 32x32 tiles, 2x2 register blocking ----------------
__global__ __launch_bounds__(256) void k_dmat(const unsigned long long* __restrict__ packed,
                                              const int* __restrict__ order1,
                                              const int* __restrict__ e_count,
                                              const int* __restrict__ e_label,
                                              float* __restrict__ dmat) {
    int bi = blockIdx.x, bj = blockIdx.y;
    int r = threadIdx.x >> 4, c = threadIdx.x & 15;
    int i0 = bi * 32 + 2 * r, j0 = bj * 32 + 2 * c;
    if (bi > bj) {  // whole tile lower-triangle -> zeros
        #pragma unroll
        for (int di = 0; di < 2; di++)
            #pragma unroll
            for (int dj = 0; dj < 2; dj++) {
                int i = i0 + di, j = j0 + dj;
                if (i < PRE && j < PRE) dmat[i * PRE + j] = 0.0f;
            }
        return;
    }
    __shared__ unsigned long long A[32][65];
    __shared__ unsigned long long B[32][65];
    int i00 = 0, i01 = 0, i10 = 0, i11 = 0;
    for (int ch = 0; ch < 6; ch++) {
        for (int l = threadIdx.x; l < 2048; l += 256) {
            int rr = l >> 6, ww = l & 63;
            int ii = bi * 32 + rr;
            int o = (ii < PRE) ? order1[ii] : -1;
            A[rr][ww] = (o >= 0) ? packed[(size_t)o * WORDS + ch * 64 + ww] : 0ull;
            int jj = bj * 32 + rr;
            int o2 = (jj < PRE) ? order1[jj] : -1;
            B[rr][ww] = (o2 >= 0) ? packed[(size_t)o2 * WORDS + ch * 64 + ww] : 0ull;
        }
        __syncthreads();
        #pragma unroll
        for (int w = 0; w < 64; w++) {
            unsigned long long a0 = A[2*r][w],   a1 = A[2*r+1][w];
            unsigned long long b0 = B[2*c][w],   b1 = B[2*c+1][w];
            i00 += __popcll(a0 & b0);
            i01 += __popcll(a0 & b1);
            i10 += __popcll(a1 & b0);
            i11 += __popcll(a1 & b1);
        }
        __syncthreads();
    }
    int vI[2][2] = {{i00, i01}, {i10, i11}};
    #pragma unroll
    for (int di = 0; di < 2; di++)
        #pragma unroll
        for (int dj = 0; dj < 2; dj++) {
            int i = i0 + di, j = j0 + dj;
            if (i < PRE && j < PRE) {
                float d = 0.0f;
                if (i < j) {
                    int oi = order1[i], oj = order1[j];
                    if (e_label[oi] == e_label[oj]) {
                        long long inter = vI[di][dj];
                        double un = (double)(e_count[oi] + e_count[oj]) - (double)inter;
                        d = (float)((double)inter / fmax(un, 1e-6));
                    }
                }
                dmat[i * PRE + j] = d;
            }
        }
}

// ---------------- compensate + coef (exp-hoisted) + (last block) sort2 ----------------
__global__ __launch_bounds__(128) void k_compcoef(const float* __restrict__ dmat,
                                                  const double* __restrict__ score_s,
                                                  double* __restrict__ ns,
                                                  unsigned* __restrict__ counters,
                                                  const int* __restrict__ order1,
                                                  const int* __restrict__ e_label,
                                                  float* __restrict__ out,
                                                  int* __restrict__ final_e) {
    __shared__ double sw0[PRE];   // 0.5*comp[i]^2
    int t = threadIdx.x;
    for (int col = t; col < PRE; col += 128) {
        float m = 0.0f;
        for (int i = 0; i < PRE; i++) m = fmaxf(m, dmat[i * PRE + col]);
        sw0[col] = (double)m * (double)m * 0.5;
    }
    __syncthreads();
    int col = blockIdx.x * 128 + t;
    if (col < PRE) {
        // min_i exp(w_i) == exp(min_i w_i)  (exp monotone)
        double wmin = 1e300;
        for (int i = 0; i < PRE; i++) {
            float d = dmat[i * PRE + col];
            double w = sw0[i] - (double)d * (double)d * 0.5;
            wmin = fmin(wmin, w);
        }
        double s = score_s[col] * exp(wmin);
        if (s < 0.05) s = 0.0;
        ns[col] = s;
    }
    // ---- ticket: last of 4 blocks runs sort2 ----
    __shared__ int amLast;
    __threadfence();
    __syncthreads();
    if (t == 0) amLast = (atomicAdd(&counters[5], 1u) == gridDim.x - 1);
    __syncthreads();
    if (!amLast) return;
    __threadfence();
    __shared__ unsigned long long sb[512];
    __shared__ int si[512];
    for (int i = t; i < 512; i += 128) {
        sb[i] = (i < PRE) ? (unsigned long long)__double_as_longlong(ns[i]) : 0ull;
        si[i] = i;
    }
    __syncthreads();
    for (int sz = 2; sz <= 512; sz <<= 1) {
        for (int j = sz >> 1; j > 0; j >>= 1) {
            for (int i = t; i < 512; i += 128) {
                int ixj = i ^ j;
                if (ixj > i) {
                    unsigned long long as = sb[i], bs = sb[ixj];
                    int ai = si[i], bi = si[ixj];
                    bool up = ((i & sz) == 0);
                    bool aB = before_key(as, ai, bs, bi);
                    bool sw = up ? (!aB) : aB;
                    if (sw) { sb[i] = bs; sb[ixj] = as; si[i] = bi; si[ixj] = ai; }
                }
            }
            __syncthreads();
        }
    }
    if (t < MAXI) {
        double s = __longlong_as_double((long long)sb[t]);
        int p = si[t];
        int e = order1[p];
        out[t] = (float)s;
        out[MAXI + t] = (float)e_label[e];
        final_e[t] = e;
    }
}

// ---------------- upsample 4x bilinear + threshold + bbox + (last block per f) boxes ----------------
// Grid: (UPS_BLOCKS, MAXI). Block covers exactly 16 output rows; the 6 needed
// feature rows are staged in LDS. Nontemporal float4 stores for the 157 MB output.
__global__ __launch_bounds__(256) void k_upsample(const float* __restrict__ seg,
                                                  const int* __restrict__ final_e,
                                                  const int* __restrict__ e_gidx,
                                                  float* __restrict__ out,
                                                  int* __restrict__ boxes_i,
                                                  unsigned* __restrict__ done) {
    int f = blockIdx.y;
    int e = final_e[f];
    const float* fm = seg + (size_t)e_gidx[e] * HW;
    float* obase = out + 200 + (size_t)f * OPIX;   // 800 B offset: 16B-aligned
    __shared__ float S[6 * 192];
    int rbase = 4 * (int)blockIdx.x - 1;
    for (int idx = threadIdx.x; idx < 6 * 192; idx += 256) {
        int rr = idx / 192, cc = idx - rr * 192;
        int src = min(max(rbase + rr, 0), FH - 1);
        S[idx] = fm[src * FW + cc];
    }
    __syncthreads();
    int xmin = 1 << 20, xmax = -1, ymin = 1 << 20, ymax = -1;
    int base = blockIdx.x * UPS_GPB + threadIdx.x;
    #pragma unroll
    for (int k = 0; k < UPS_ITERS; k++) {
        int p = base + k * 256;
        int oy = p / 192;
        int gx = p - oy * 192;
        float iny = (float)oy * 0.25f - 0.375f;
        int y0 = (int)floorf(iny);
        float fy = iny - (float)y0;
        int ly = y0 - rbase;                  // 0..4
        int xm = max(gx - 1, 0), xp = min(gx + 1, FW - 1);
        const float* r0 = S + ly * 192;
        const float* r1 = S + (ly + 1) * 192;
        float am = r0[xm], a0 = r0[gx], ap = r0[xp];
        float bm = r1[xm], b0 = r1[gx], bp = r1[xp];
        float gy = 1.0f - fy;
        float vm = __fadd_rn(__fmul_rn(am, gy), __fmul_rn(bm, fy));
        float v0 = __fadd_rn(__fmul_rn(a0, gy), __fmul_rn(b0, fy));
        float vp = __fadd_rn(__fmul_rn(ap, gy), __fmul_rn(bp, fy));
        float o0 = __fadd_rn(__fmul_rn(vm, 0.375f), __fmul_rn(v0, 0.625f));
        float o1 = __fadd_rn(__fmul_rn(vm, 0.125f), __fmul_rn(v0, 0.875f));
        float o2 = __fadd_rn(__fmul_rn(v0, 0.875f), __fmul_rn(vp, 0.125f));
        float o3 = __fadd_rn(__fmul_rn(v0, 0.625f), __fmul_rn(vp, 0.375f));
        bool m0 = o0 > 0.5f, m1 = o1 > 0.5f, m2 = o2 > 0.5f, m3 = o3 > 0.5f;
        f4_t w;
        w.x = m0 ? 1.0f : 0.0f;
        w.y = m1 ? 1.0f : 0.0f;
        w.z = m2 ? 1.0f : 0.0f;
        w.w = m3 ? 1.0f : 0.0f;
        __builtin_nontemporal_store(w, (f4_t*)(obase + (size_t)p * 4));
        if (m0 | m1 | m2 | m3) {
            int ox0 = gx * 4;
            ymin = min(ymin, oy);
            ymax = max(ymax, oy);
            int lo = m0 ? 0 : (m1 ? 1 : (m2 ? 2 : 3));
            int hi = m3 ? 3 : (m2 ? 2 : (m1 ? 1 : 0));
            xmin = min(xmin, ox0 + lo);
            xmax = max(xmax, ox0 + hi);
        }
    }
    for (int off = 32; off > 0; off >>= 1) {
        xmin = min(xmin, __shfl_down(xmin, off));
        xmax = max(xmax, __shfl_down(xmax, off));
        ymin = min(ymin, __shfl_down(ymin, off));
        ymax = max(ymax, __shfl_down(ymax, off));
    }
    __shared__ int sxm[4], sxM[4], sym[4], syM[4];
    int lane = threadIdx.x & 63, wv = threadIdx.x >> 6;
    if (lane == 0) { sxm[wv] = xmin; sxM[wv] = xmax; sym[wv] = ymin; syM[wv] = ymax; }
    __syncthreads();
    if (threadIdx.x == 0) {
        int mnx = min(min(sxm[0], sxm[1]), min(sxm[2], sxm[3]));
        int mxx = max(max(sxM[0], sxM[1]), max(sxM[2], sxM[3]));
        int mny = min(min(sym[0], sym[1]), min(sym[2], sym[3]));
        int mxy = max(max(syM[0], syM[1]), max(syM[2], syM[3]));
        if (mxx >= 0) {
            atomicMin(&boxes_i[f * 4 + 0], mnx);
            atomicMin(&boxes_i[f * 4 + 1], mny);
            atomicMax(&boxes_i[f * 4 + 2], mxx);
            atomicMax(&boxes_i[f * 4 + 3], mxy);
        }
        __threadfence();
        unsigned tk = atomicAdd(&done[f], 1u);
        if (tk == UPS_BLOCKS - 1) {
            __threadfence();
            float sc = out[f];
            float mlt = (sc > 0.0f) ? 1.0f : 0.0f;
            size_t bb = 200 + (size_t)MAXI * OPIX;
            out[bb + f * 4 + 0] = (float)boxes_i[f * 4 + 0] * mlt;
            out[bb + f * 4 + 1] = (float)boxes_i[f * 4 + 1] * mlt;
            out[bb + f * 4 + 2] = (float)boxes_i[f * 4 + 2] * mlt;
            out[bb + f * 4 + 3] = (float)boxes_i[f * 4 + 3] * mlt;
        }
    }
}

extern "C" void kernel_launch(void* const* d_in, const int* in_sizes, int n_in,
                              void* d_out, int out_size, void* d_ws, size_t ws_size,
                              hipStream_t stream) {
    const float* cate = (const float*)d_in[0];
    const float* seg  = (const float*)d_in[1];
    float* out = (float*)d_out;
    char* ws = (char*)d_ws;

    unsigned* hist       = (unsigned*)(ws + OFF_HIST);
    unsigned* counters   = (unsigned*)(ws + OFF_CNT);
    unsigned long long* keybuf = (unsigned long long*)(ws + OFF_KEYBUF);
    int* e_gidx          = (int*)(ws + OFF_EGIDX);
    int* e_label         = (int*)(ws + OFF_ELABEL);
    int* e_count         = (int*)(ws + OFF_ECOUNT);
    float* tk_score      = (float*)(ws + OFF_TKSCORE);
    double* e_score1     = (double*)(ws + OFF_ESCORE1);
    int* order1          = (int*)(ws + OFF_ORDER1);
    double* score_s      = (double*)(ws + OFF_SCORES);
    double* ns           = (double*)(ws + OFF_NS);
    int* final_e         = (int*)(ws + OFF_FINALE);
    int* boxes_i         = (int*)(ws + OFF_BOXESI);
    unsigned* done       = (unsigned*)(ws + OFF_DONE);
    unsigned long long* packed = (unsigned long long*)(ws + OFF_PACKED);
    float* dmat          = (float*)(ws + OFF_DMAT);

    hipLaunchKernelGGL(k_init, dim3(64), dim3(256), 0, stream, hist, counters, boxes_i, done);
    hipLaunchKernelGGL(k_hist, dim3((NFLAT / 4 + 255) / 256), dim3(256), 0, stream,
                       (const float4*)cate, hist, counters);
    hipLaunchKernelGGL(k_collect, dim3((NFLAT / 4 + 255) / 256), dim3(256), 0, stream,
                       (const float4*)cate, counters, keybuf);
    hipLaunchKernelGGL(k_sort_collect, dim3(1), dim3(1024), 0, stream, keybuf, counters,
                       e_gidx, e_label, tk_score);
    hipLaunchKernelGGL(k_maskstats, dim3(PRE), dim3(256), 0, stream, seg, e_gidx, tk_score,
                       packed, e_count, e_score1, counters, order1, score_s);
    hipLaunchKernelGGL(k_dmat, dim3(16, 16), dim3(256), 0, stream, packed, order1, e_count,
                       e_label, dmat);
    hipLaunchKernelGGL(k_compcoef, dim3(4), dim3(128), 0, stream, dmat, score_s, ns, counters,
                       order1, e_label, out, final_e);
    hipLaunchKernelGGL(k_upsample, dim3(UPS_BLOCKS, MAXI), dim3(256), 0, stream, seg, final_e,
                       e_gidx, out, boxes_i, done);
}